// Round 9
// baseline (262.582 us; speedup 1.0000x reference)
//
#include <hip/hip_runtime.h>

// TreeAttentionV2: B=8, T=1024, C=1024 (L=4,R=256), H=16, hd=64.
// Pipeline (all fp16 MFMA, fp32 accumulate):
//   1. prep:      x fp32 -> xh fp16 AND both weight transposes (one launch)
//   2. gemm_qkv:  qn/kP/vP = xh @ waT^T + b_attn. 256x256x64 8-phase; fused-pack epilogue
//                 (16x16 fragment orders, r4/r6/r8-proven, UNTOUCHED); XCD swizzle.
//   3. attn v10b: 32-row q-tile, 8 waves, k-sliced, XCD swizzle. 32x32x16 MFMAs with P
//                 IN REGISTERS (no E LDS matrix): S^T regs repacked to PV A-frags via
//                 v_permlane32_swap_b32 (register-only; r7's shfl_xor->ds_bpermute cost
//                 removed). Fragments GATHERED from the proven 16x16-order kP/vP buffers
//                 (16-lane-contiguous 256B segments). exp2 no-clamp; setprio on MFMA.
//   4. gemm_proj: out = y @ wpT^T + b_proj (256x128 8-phase, 1 exact round, XCD swizzle)
//
// Workspace (88 MiB):
//   [0,16M)   y ; [16M,32M) qn ; [32M,48M) kP ; [48M,64M) vP
//   [64M,70M) waT ; [70M,72M) wpT ; [72M,88M) xh (dead after gemm_qkv)

typedef _Float16 half8 __attribute__((ext_vector_type(8)));
typedef _Float16 half4_t __attribute__((ext_vector_type(4)));
typedef float floatx4 __attribute__((ext_vector_type(4)));
typedef float floatx16 __attribute__((ext_vector_type(16)));
typedef unsigned int uint4v __attribute__((ext_vector_type(4)));

__device__ __forceinline__ void gl2lds16(const void* gsrc, void* lds) {
    __builtin_amdgcn_global_load_lds(
        (const __attribute__((address_space(1))) unsigned int*)gsrc,
        (__attribute__((address_space(3))) unsigned int*)lds,
        16, 0, 0);
}

// pack two f32 -> dword of 2 fp16 (scalar casts; compiler emits cvt+pack)
__device__ __forceinline__ unsigned pkh(float a, float b) {
    _Float16 ha = (_Float16)a, hb = (_Float16)b;
    unsigned short ua = __builtin_bit_cast(unsigned short, ha);
    unsigned short ub = __builtin_bit_cast(unsigned short, hb);
    return (unsigned)ua | ((unsigned)ub << 16);
}

// ---------------- prep: conv_x (blocks 0..4095) + weight transposes (4096..5119) ----------
__global__ __launch_bounds__(256) void prep(const float4* __restrict__ x4,
                                            _Float16* __restrict__ xh,
                                            const float* __restrict__ wa,
                                            _Float16* __restrict__ waT,
                                            const float* __restrict__ wp,
                                            _Float16* __restrict__ wpT) {
    __shared__ _Float16 t[64 * 65];
    int bid = blockIdx.x;
    if (bid < 4096) {
        int idx = bid * 256 + threadIdx.x;
#pragma unroll
        for (int i = idx; i < 2097152; i += 1048576) {
            float4 v = x4[i];
            half4_t h = { (_Float16)v.x, (_Float16)v.y, (_Float16)v.z, (_Float16)v.w };
            *(half4_t*)(xh + (size_t)i * 4) = h;
        }
    } else {
        int tt = bid - 4096;
        int by = tt & 15, bx = tt >> 4;
        const float* in = wa; _Float16* out = waT; int C = 3072;
        if (bx >= 48) { bx -= 48; in = wp; out = wpT; C = 1024; }
#pragma unroll
        for (int it = 0; it < 16; ++it) {
            int idx = it * 256 + threadIdx.x;
            int r = idx >> 6, c = idx & 63;
            t[c * 65 + r] = (_Float16)in[(size_t)(by * 64 + r) * C + bx * 64 + c];
        }
        __syncthreads();
#pragma unroll
        for (int it = 0; it < 16; ++it) {
            int idx = it * 256 + threadIdx.x;
            int rn = idx >> 6, ck = idx & 63;
            out[(size_t)(bx * 64 + rn) * 1024 + by * 64 + ck] = t[rn * 65 + ck];
        }
    }
}

// common pipeline helpers
#define GBAR __builtin_amdgcn_s_barrier()
#define WLGKM do { asm volatile("s_waitcnt lgkmcnt(0)" ::: "memory"); } while (0)
#define WVM2  do { asm volatile("s_waitcnt vmcnt(2)"   ::: "memory"); } while (0)
#define WVM4  do { asm volatile("s_waitcnt vmcnt(4)"   ::: "memory"); } while (0)
#define WVM0  do { asm volatile("s_waitcnt vmcnt(0)"   ::: "memory"); } while (0)

// ================= gemm_qkv: 256x256 8-phase + fused-pack epilogue + XCD swizzle ======
// BM=256, BN=256, BK=64, K=1024. 512 threads = 8 waves (2M x 4N), per-wave 128x64.
// LDS 128KB. XOR-swizzle via inverse-swizzled global source. WVM4 at P4/P8 only.
// kP chunk c holds K[t=(c>>7&63)*16+(c&15)][d=(c>>6&1)*32+((c>>4)&3)*8+j]  (c per bh<<13)
// vP chunk c holds V^T[d=((c&255)>>6)*16+(c&15)][k=(c>>8&31)*32+((c>>4)&3)*8+j] (per bh<<13)

#define WLDA(buf, rg)                                                                         \
    do {                                                                                      \
        _Pragma("unroll") for (int i = 0; i < 4; ++i) {                                       \
            int r_ = wm * 128 + ((rg) * 4 + i) * 16 + l15;                                    \
            _Pragma("unroll") for (int kk = 0; kk < 2; ++kk)                                  \
                a[i][kk] = *(const half8*)(sA + (buf) * 32768 + r_ * 128 +                    \
                                           ((((kk << 2) + quad) ^ (r_ & 7)) << 4));           \
        }                                                                                     \
    } while (0)

#define WLDB(buf, cg, bb)                                                                     \
    do {                                                                                      \
        _Pragma("unroll") for (int j = 0; j < 2; ++j) {                                       \
            int r_ = wn * 64 + ((cg) * 2 + j) * 16 + l15;                                     \
            _Pragma("unroll") for (int kk = 0; kk < 2; ++kk)                                  \
                bb[j][kk] = *(const half8*)(sB + (buf) * 32768 + r_ * 128 +                   \
                                            ((((kk << 2) + quad) ^ (r_ & 7)) << 4));          \
        }                                                                                     \
    } while (0)

#define WMMA(rg, cg, bb)                                                                      \
    do {                                                                                      \
        __builtin_amdgcn_s_setprio(1);                                                        \
        _Pragma("unroll") for (int kk = 0; kk < 2; ++kk)                                      \
            _Pragma("unroll") for (int i = 0; i < 4; ++i)                                     \
                _Pragma("unroll") for (int j = 0; j < 2; ++j)                                  \
                    acc[(rg) * 4 + i][(cg) * 2 + j] = __builtin_amdgcn_mfma_f32_16x16x32_f16( \
                        a[i][kk], bb[j][kk], acc[(rg) * 4 + i][(cg) * 2 + j], 0, 0, 0);       \
        __builtin_amdgcn_s_setprio(0);                                                        \
    } while (0)

__global__ __launch_bounds__(512, 2) void gemm_qkv(const _Float16* __restrict__ A,
                                                   const _Float16* __restrict__ BT,
                                                   const float* __restrict__ bias,
                                                   _Float16* __restrict__ qno,
                                                   _Float16* __restrict__ kPo,
                                                   _Float16* __restrict__ vPo) {
    __shared__ __attribute__((aligned(16))) char lds[131072];
    char* sA = lds;           // + buf*32768 + half*16384 + rnd*8192
    char* sB = lds + 65536;
    int tid = threadIdx.x;
    int W = tid >> 6, lane = tid & 63, quad = lane >> 4, l15 = lane & 15;
    int wm = W >> 2, wn = W & 3;
    int flat = blockIdx.y * 12 + blockIdx.x;
    int swz = (flat & 7) * 48 + (flat >> 3);   // bijective, 384 % 8 == 0
    int m0 = (swz / 12) * 256, n0 = (swz % 12) * 256;

    auto stA = [&](int buf, int half, int k0) {
#pragma unroll
        for (int rnd = 0; rnd < 2; ++rnd) {
            int c = rnd * 512 + tid;
            int row = c >> 3;
            int q = (c & 7) ^ (row & 7);
            const _Float16* src = A + (size_t)(m0 + half * 128 + row) * 1024 + k0 + q * 8;
            int off = __builtin_amdgcn_readfirstlane(buf * 32768 + half * 16384 +
                                                     rnd * 8192 + (W << 10));
            gl2lds16(src, sA + off);
        }
    };
    auto stB = [&](int buf, int half, int k0) {
#pragma unroll
        for (int rnd = 0; rnd < 2; ++rnd) {
            int c = rnd * 512 + tid;
            int row = c >> 3;
            int q = (c & 7) ^ (row & 7);
            const _Float16* src = BT + (size_t)(n0 + half * 128 + row) * 1024 + k0 + q * 8;
            int off = __builtin_amdgcn_readfirstlane(buf * 32768 + half * 16384 +
                                                     rnd * 8192 + (W << 10));
            gl2lds16(src, sB + off);
        }
    };

    half8 a[4][2], b0[2][2], b1[2][2];
    floatx4 acc[8][4] = {};

    stA(0, 0, 0); stA(0, 1, 0);
    stB(0, 0, 0); stB(0, 1, 0);
    stB(1, 0, 64); stB(1, 1, 64);
    WVM4;
    GBAR;

#pragma unroll 1
    for (int t = 0; t < 16; t += 2) {
        int k1 = (t + 1) << 6;
        int k2 = ((t + 2) & 15) << 6;   // wraps last iter: garbage into dead bufs
        int k3 = ((t + 3) & 15) << 6;
        WLDA(0, 0); WLDB(0, 0, b0); stA(1, 0, k1);
        GBAR; WLGKM; WMMA(0, 0, b0); GBAR;                 // P1
        WLDB(0, 1, b1); stA(1, 1, k1);
        GBAR; WLGKM; WMMA(0, 1, b1); GBAR;                 // P2
        WLDA(0, 1); stB(0, 0, k2);
        GBAR; WLGKM; WMMA(1, 1, b1); GBAR;                 // P3
        stB(0, 1, k2); WVM4;
        GBAR; WLGKM; WMMA(1, 0, b0); GBAR;                 // P4
        WLDA(1, 0); WLDB(1, 0, b0); stA(0, 0, k2);
        GBAR; WLGKM; WMMA(0, 0, b0); GBAR;                 // P5
        WLDB(1, 1, b1); stA(0, 1, k2);
        GBAR; WLGKM; WMMA(0, 1, b1); GBAR;                 // P6
        WLDA(1, 1); stB(1, 0, k3);
        GBAR; WLGKM; WMMA(1, 1, b1); GBAR;                 // P7
        stB(1, 1, k3); WVM4;
        GBAR; WLGKM; WMMA(1, 0, b0); GBAR;                 // P8
    }

    // ---- fused-pack epilogue: two column-half passes (128 cols each) ----
    WVM0;          // trailing prefetch DMA must land before LDS reuse
    GBAR;
    int sec = n0 >> 10;          // 0=Q 1=K 2=V (256-tiles never straddle 1024)
    int b = m0 >> 10;            // batch (BM=256 stays within one b)
    int tb = m0 & 1023;          // token base
#pragma unroll 1
    for (int p = 0; p < 2; ++p) {
        if (p) __syncthreads();          // pass-0 reads done before restage
        if (sec == 2) {
            // V: stage transposed [lc=128][m=256], row stride 528B
            if ((wn >> 1) == p) {
#pragma unroll
                for (int cf = 0; cf < 4; ++cf) {
                    int lc = (wn & 1) * 64 + cf * 16 + l15;
                    float bv = bias[n0 + wn * 64 + cf * 16 + l15];
#pragma unroll
                    for (int rf = 0; rf < 8; ++rf) {
                        int m = wm * 128 + rf * 16 + quad * 4;   // m&7 in {0,4}: 8B aligned
                        half4_t h4;
#pragma unroll
                        for (int r = 0; r < 4; ++r) h4[r] = (_Float16)(acc[rf][cf][r] + bv);
                        *(half4_t*)(lds + lc * 528 + m * 2) = h4;
                    }
                }
            }
            __syncthreads();
            int l15v = tid & 15;
            int moct = W * 4 + ((tid >> 4) & 3);     // m-octet 0..31
            int t = tb + moct * 8;
            int kbv = (t >> 5) & 31, quad_v = (t >> 3) & 3;
            int nbV = (n0 & 1023) + p * 128;
#pragma unroll
            for (int i = 0; i < 8; ++i) {
                int hh = i >> 2, cf = i & 3;
                int n = hh * 64 + cf * 16 + l15v;
                half8 v = *(const half8*)(lds + n * 528 + (moct << 4));
                int gcol = nbV + n;
                int h = gcol >> 6, d = gcol & 63;
                size_t chunk = (size_t)((b * 16 + h) * 32 + kbv) * 256 +
                               (d >> 4) * 64 + quad_v * 16 + (d & 15);
                *(half8*)(vPo + chunk * 8) = v;
            }
        } else {
            // Q/K: stage [m=256][lc=128], row stride 272B
            if ((wn >> 1) == p) {
#pragma unroll
                for (int cf = 0; cf < 4; ++cf) {
                    int lc = (wn & 1) * 64 + cf * 16 + l15;
                    float bv = bias[n0 + wn * 64 + cf * 16 + l15];
#pragma unroll
                    for (int rf = 0; rf < 8; ++rf) {
                        int m = wm * 128 + rf * 16 + quad * 4;
#pragma unroll
                        for (int r = 0; r < 4; ++r)
                            *(_Float16*)(lds + (m + r) * 272 + lc * 2) =
                                (_Float16)(acc[rf][cf][r] + bv);
                    }
                }
            }
            __syncthreads();
            int nb = (n0 & 1023) + p * 128;
            if (sec == 0) {
                int noct = tid & 15;
#pragma unroll
                for (int i = 0; i < 8; ++i) {
                    int m = i * 32 + (tid >> 4);
                    half8 v = *(const half8*)(lds + m * 272 + (noct << 4));
                    *(half8*)(qno + (size_t)(b * 1024 + tb + m) * 1024 + nb + noct * 8) = v;
                }
            } else {
                int l15k = tid & 15, noct = (tid >> 4) & 15;
#pragma unroll
                for (int i = 0; i < 8; ++i) {
                    int mb = i * 2 + (tid >> 8);
                    int m = mb * 16 + l15k;
                    half8 v = *(const half8*)(lds + m * 272 + (noct << 4));
                    int gcol = nb + noct * 8;
                    int h = gcol >> 6, d0 = gcol & 63;
                    int t = tb + m;
                    size_t chunk = (size_t)((b * 16 + h) * 64 + (t >> 4)) * 128 +
                                   (d0 >> 5) * 64 + ((d0 >> 3) & 3) * 16 + l15k;
                    *(half8*)(kPo + chunk * 8) = v;
                }
            }
        }
    }
}

// ================= gemm_proj: 256x128 8-phase, f32 out, XCD swizzle =================
#define LDA(buf, rg)                                                                          \
    do {                                                                                      \
        _Pragma("unroll") for (int i = 0; i < 2; ++i) {                                       \
            int r_ = wm * 64 + ((rg) * 2 + i) * 16 + l15;                                     \
            _Pragma("unroll") for (int kk = 0; kk < 2; ++kk)                                  \
                a[i][kk] = *(const half8*)(sA + (buf) * 32768 + r_ * 128 +                    \
                                           ((((kk << 2) + quad) ^ (r_ & 7)) << 4));           \
        }                                                                                     \
    } while (0)

#define LDB(buf, cg, bb)                                                                      \
    do {                                                                                      \
        _Pragma("unroll") for (int j = 0; j < 2; ++j) {                                       \
            int r_ = wn * 64 + ((cg) * 2 + j) * 16 + l15;                                     \
            _Pragma("unroll") for (int kk = 0; kk < 2; ++kk)                                  \
                bb[j][kk] = *(const half8*)(sB + (buf) * 16384 + r_ * 128 +                   \
                                            ((((kk << 2) + quad) ^ (r_ & 7)) << 4));          \
        }                                                                                     \
    } while (0)

#define MMA(rg, cg, bb)                                                                       \
    do {                                                                                      \
        __builtin_amdgcn_s_setprio(1);                                                        \
        _Pragma("unroll") for (int kk = 0; kk < 2; ++kk)                                      \
            _Pragma("unroll") for (int i = 0; i < 2; ++i)                                     \
                _Pragma("unroll") for (int j = 0; j < 2; ++j)                                  \
                    acc[(rg) * 2 + i][(cg) * 2 + j] = __builtin_amdgcn_mfma_f32_16x16x32_f16( \
                        a[i][kk], bb[j][kk], acc[(rg) * 2 + i][(cg) * 2 + j], 0, 0, 0);       \
        __builtin_amdgcn_s_setprio(0);                                                        \
    } while (0)

__global__ __launch_bounds__(512, 2) void gemm_proj(const _Float16* __restrict__ A,
                                                    const _Float16* __restrict__ BT,
                                                    const float* __restrict__ bias,
                                                    float* __restrict__ o0, int N) {
    __shared__ __attribute__((aligned(16))) char lds[98304];
    char* sA = lds;
    char* sB = lds + 65536;
    int tid = threadIdx.x;
    int W = tid >> 6, lane = tid & 63, quad = lane >> 4, l15 = lane & 15;
    int wm = W >> 1, wn = W & 1;
    int flat = blockIdx.y * 8 + blockIdx.x;
    int swz = (flat & 7) * 32 + (flat >> 3);
    int m0 = (swz >> 3) * 256, n0 = (swz & 7) * 128;

    auto stA = [&](int buf, int half, int k0) {
#pragma unroll
        for (int rnd = 0; rnd < 2; ++rnd) {
            int c = rnd * 512 + tid;
            int row = c >> 3;
            int q = (c & 7) ^ (row & 7);
            const _Float16* src = A + (size_t)(m0 + half * 128 + row) * 1024 + k0 + q * 8;
            int off = __builtin_amdgcn_readfirstlane(buf * 32768 + half * 16384 +
                                                     rnd * 8192 + (W << 10));
            gl2lds16(src, sA + off);
        }
    };
    auto stB = [&](int buf, int half, int k0) {
        int row = tid >> 3;
        int q = (tid & 7) ^ (row & 7);
        const _Float16* src = BT + (size_t)(n0 + half * 64 + row) * 1024 + k0 + q * 8;
        int off = __builtin_amdgcn_readfirstlane(buf * 16384 + half * 8192 + (W << 10));
        gl2lds16(src, sB + off);
    };

    half8 a[2][2], b0[2][2], b1[2][2];
    floatx4 acc[4][4] = {};

    stA(0, 0, 0); stA(0, 1, 0);
    stB(0, 0, 0); stB(0, 1, 0);
    stB(1, 0, 64); stB(1, 1, 64);
    WVM2;
    GBAR;

#pragma unroll 1
    for (int t = 0; t < 16; t += 2) {
        int k1 = (t + 1) << 6;
        int k2 = ((t + 2) & 15) << 6;
        int k3 = ((t + 3) & 15) << 6;
        LDA(0, 0); LDB(0, 0, b0); stA(1, 0, k1);
        GBAR; WLGKM; MMA(0, 0, b0); GBAR;
        LDB(0, 1, b1); stA(1, 1, k1);
        GBAR; WLGKM; MMA(0, 1, b1); GBAR;
        LDA(0, 1); stB(0, 0, k2);
        GBAR; WLGKM; MMA(1, 1, b1); GBAR;
        stB(0, 1, k2); WVM2;
        GBAR; WLGKM; MMA(1, 0, b0); GBAR;
        LDA(1, 0); LDB(1, 0, b0); stA(0, 0, k2);
        GBAR; WLGKM; MMA(0, 0, b0); GBAR;
        LDB(1, 1, b1); stA(0, 1, k2);
        GBAR; WLGKM; MMA(0, 1, b1); GBAR;
        LDA(1, 1); stB(1, 0, k3);
        GBAR; WLGKM; MMA(1, 1, b1); GBAR;
        stB(1, 1, k3); WVM2;
        GBAR; WLGKM; MMA(1, 0, b0); GBAR;
    }

#pragma unroll
    for (int cf = 0; cf < 4; ++cf) {
        int gn = n0 + wn * 64 + cf * 16 + l15;
        float bv = bias[gn];
#pragma unroll
        for (int rf = 0; rf < 4; ++rf) {
            int gmBase = m0 + wm * 64 + rf * 16 + quad * 4;
#pragma unroll
            for (int r = 0; r < 4; ++r)
                o0[(size_t)(gmBase + r) * N + gn] = acc[rf][cf][r] + bv;
        }
    }
}

// ------------------------------- attention v10b -------------------------------
// grid 4096 (32 qt x 128 bh), XCD-swizzled; 512 threads = 8 waves; wave w owns k-slice
// [w*128, w*128+128) as 4 kb-blocks of 32 k.
// Fragments gathered from the PROVEN 16x16-order kP/vP (writer formulas inverted):
//   kP chunk  c = (t>>4)*128 + (d>>5)*64 + ((d>>3)&3)*16 + (t&15)
//   vP chunk  c = (k>>5)*256 + (d>>4)*64 + ((k>>3)&3)*16 + (d&15)
// Per kb: S^T = 4x mfma_32x32x16(K,Q) chained -> 16 f32 (col q=lane&31, row
// k=(r&3)+8(r>>2)+4hi). exp2 (no clamp) -> pkh pairs -> v_permlane32_swap_b32
// redistributes to PV A-frag layout (k'=8hi+j): swap(P01,P45)->{F0,F2},
// swap(P23,P67)->{F1,F3}. NO E LDS matrix. Normalize+threshold fused in fp16
// (inv uniform per lane). PV 32x32x16. Partials -> wave-own red cols; 2 barriers.
__global__ __launch_bounds__(512, 4) void attn(const _Float16* __restrict__ qn,
                                               const _Float16* __restrict__ kP,
                                               const _Float16* __restrict__ vP,
                                               _Float16* __restrict__ y) {
    __shared__ __attribute__((aligned(16))) char red[65536];   // 32q x (8w x 64d) f32
    __shared__ float lsum[8][32];
    int tid = threadIdx.x;
    int W = tid >> 6, lane = tid & 63;
    int l31 = lane & 31, hi = lane >> 5;
    int flat = blockIdx.y * 32 + blockIdx.x;
    int swz = (flat & 7) * 512 + (flat >> 3);     // bijective, 4096 % 8 == 0
    int qt = swz & 31, bh = swz >> 5;
    int b = bh >> 4, h = bh & 15;
    int q0 = qt * 32;

    const _Float16* kPb = kP + (size_t)bh * 8192 * 8;   // this head's 8192 chunks
    const _Float16* vPb = vP + (size_t)bh * 8192 * 8;

    // --- Q as 32x32x16 B-frags: lane holds Q[q=l31][d=ks*16+hi*8+j] ---
    half8 bq[4];
#pragma unroll
    for (int ks = 0; ks < 4; ++ks)
        bq[ks] = *(const half8*)(qn + (size_t)(b * 1024 + q0 + l31) * 1024 +
                                 h * 64 + ks * 16 + hi * 8);

    // --- Phase 1: S^T per kb; exp2; repack to PV A-frags (register-only) ---
    half8 pd[4][2];
    float lpA = 0.f, lpB = 0.f;
#pragma unroll
    for (int kb = 0; kb < 4; ++kb) {
        // t = W*128 + kb*32 + l31 -> t>>4 = W*8+kb*2+(l31>>4), t&15 = l31&15
        int cbase = (W * 8 + kb * 2 + (l31 >> 4)) * 128 + (l31 & 15);
        half8 ak0 = *(const half8*)(kPb + (size_t)(cbase + hi * 16) * 8);        // d0=hi*8
        half8 ak1 = *(const half8*)(kPb + (size_t)(cbase + (2 + hi) * 16) * 8);  // d0=16+hi*8
        half8 ak2 = *(const half8*)(kPb + (size_t)(cbase + 64 + hi * 16) * 8);   // d0=32+hi*8
        half8 ak3 = *(const half8*)(kPb + (size_t)(cbase + 64 + (2 + hi) * 16) * 8);
        floatx16 s = {};
        __builtin_amdgcn_s_setprio(1);
        s = __builtin_amdgcn_mfma_f32_32x32x16_f16(ak0, bq[0], s, 0, 0, 0);
        s = __builtin_amdgcn_mfma_f32_32x32x16_f16(ak1, bq[1], s, 0, 0, 0);
        s = __builtin_amdgcn_mfma_f32_32x32x16_f16(ak2, bq[2], s, 0, 0, 0);
        s = __builtin_amdgcn_mfma_f32_32x32x16_f16(ak3, bq[3], s, 0, 0, 0);
        __builtin_amdgcn_s_setprio(0);
        float e[16];
#pragma unroll
        for (int r = 0; r < 16; ++r)
            e[r] = __builtin_amdgcn_exp2f(s[r] * 0.18033688f);   // exp(s/8); clamp dead
        lpA += ((e[0] + e[1]) + (e[2] + e[3])) + ((e[4] + e[5]) + (e[6] + e[7]));
        lpB += ((e[8] + e[9]) + (e[10] + e[11])) + ((e[12] + e[13]) + (e[14] + e[15]));
        // rows k' = (r&3)+8*(r>>2)+4hi within chunk c2 (regs c2*8..c2*8+7).
        // A-frag needs k' = 8hi+j. v_permlane32_swap_b32(a,b): a.hi <-> b.lo.
        //   swap(P01,P45): a -> F0 (hi0: own k'{0,1}; hi1: lane-32's k'{8,9})
        //                  b -> F2 (hi0: lane+32's k'{4,5}; hi1: own k'{12,13})
#pragma unroll
        for (int c2 = 0; c2 < 2; ++c2) {
            int o = c2 * 8;
            unsigned P01 = pkh(e[o + 0], e[o + 1]);
            unsigned P23 = pkh(e[o + 2], e[o + 3]);
            unsigned P45 = pkh(e[o + 4], e[o + 5]);
            unsigned P67 = pkh(e[o + 6], e[o + 7]);
            asm("v_permlane32_swap_b32 %0, %1" : "+v"(P01), "+v"(P45));
            asm("v_permlane32_swap_b32 %0, %1" : "+v"(P23), "+v"(P67));
            uint4v F = { P01, P23, P45, P67 };   // F0,F1,F2,F3 = k'{8hi..8hi+7}
            pd[kb][c2] = __builtin_bit_cast(half8, F);
        }
    }
    {
        float lp = lpA + lpB;
        lp += __shfl_xor(lp, 32);
        if (lane < 32) lsum[W][l31] = lp;
    }
    __syncthreads();

    // --- normalize + threshold (inv uniform per lane: all P share q = l31) ---
    half8 inv8, t8, z8;
#pragma unroll
    for (int j = 0; j < 8; ++j) { t8[j] = (_Float16)(-0.001f); z8[j] = (_Float16)0.f; }
    {
        float l = 0.f;
#pragma unroll
        for (int w = 0; w < 8; ++w) l += lsum[w][l31];
        _Float16 invh = (_Float16)(1.0f / l);
#pragma unroll
        for (int j = 0; j < 8; ++j) inv8[j] = invh;
    }
#pragma unroll
    for (int kb = 0; kb < 4; ++kb)
#pragma unroll
        for (int c2 = 0; c2 < 2; ++c2) {
            pd[kb][c2] = pd[kb][c2] * inv8 + t8;                    // v_pk_fma_f16
            pd[kb][c2] = __builtin_elementwise_max(pd[kb][c2], z8); // v_pk_max_f16
        }

    // --- Phase 2: PV, 32x32x16; acc0/acc1 = d-halves over wave's 128 k ---
    floatx16 acc0 = {}, acc1 = {};
#pragma unroll
    for (int kb = 0; kb < 4; ++kb)
#pragma unroll
        for (int c2 = 0; c2 < 2; ++c2) {
            int kc = (W * 4 + kb) * 2 + c2;          // 16-k block index
            // k = kc*16+hi*8+j, d = dh*32+l31:
            // chunk = (kc>>1)*256 + (dh*2+(l31>>4))*64 + ((kc&1)*2+hi)*16 + (l31&15)
            int vbase = (kc >> 1) * 256 + (l31 >> 4) * 64 + ((kc & 1) * 2 + hi) * 16 +
                        (l31 & 15);
            half8 bv0 = *(const half8*)(vPb + (size_t)vbase * 8);
            half8 bv1 = *(const half8*)(vPb + (size_t)(vbase + 128) * 8);
            __builtin_amdgcn_s_setprio(1);
            acc0 = __builtin_amdgcn_mfma_f32_32x32x16_f16(pd[kb][c2], bv0, acc0, 0, 0, 0);
            acc1 = __builtin_amdgcn_mfma_f32_32x32x16_f16(pd[kb][c2], bv1, acc1, 0, 0, 0);
            __builtin_amdgcn_s_setprio(0);
        }

    // --- Phase 3: partials into wave-own red columns; barrier; cross-wave sum ---
    // D: col d = dh*32 + l31, row q = (r&3)+8*(r>>2)+4hi.
#pragma unroll
    for (int r = 0; r < 16; ++r) {
        int q = (r & 3) + 8 * (r >> 2) + 4 * hi;
        *(float*)(red + q * 2048 + W * 256 + l31 * 4) = acc0[r];
        *(float*)(red + q * 2048 + W * 256 + 128 + l31 * 4) = acc1[r];
    }
    __syncthreads();
    {
        int e4 = tid * 4;                 // 512 thr x 4 = 2048 = 32 rows x 64 d
        int r = e4 >> 6, c = e4 & 63;
        floatx4 s = {};
#pragma unroll
        for (int w = 0; w < 8; ++w)
            s += *(const floatx4*)(red + r * 2048 + w * 256 + c * 4);
        half4_t hv = { (_Float16)s[0], (_Float16)s[1], (_Float16)s[2], (_Float16)s[3] };
        *(half4_t*)(y + (size_t)(b * 1024 + q0 + r) * 1024 + h * 64 + c) = hv;
    }
}

// ------------------------------- launcher -------------------------------
extern "C" void kernel_launch(void* const* d_in, const int* in_sizes, int n_in,
                              void* d_out, int out_size, void* d_ws, size_t ws_size,
                              hipStream_t stream) {
    const float* x  = (const float*)d_in[0];
    const float* wa = (const float*)d_in[1];
    const float* ba = (const float*)d_in[2];
    const float* wp = (const float*)d_in[3];
    const float* bp = (const float*)d_in[4];
    float* out = (float*)d_out;

    char* ws = (char*)d_ws;
    _Float16* y   = (_Float16*)(ws);                    // [0,16M)   attn out
    _Float16* qn  = (_Float16*)(ws + 16777216);         // [16M,32M)
    _Float16* kP  = (_Float16*)(ws + 33554432);         // [32M,48M)
    _Float16* vP  = (_Float16*)(ws + 50331648);         // [48M,64M)
    _Float16* waT = (_Float16*)(ws + 67108864);         // [64M,70M)
    _Float16* wpT = (_Float16*)(ws + 73400320);         // [70M,72M)
    _Float16* xh  = (_Float16*)(ws + 75497472);         // [72M,88M) dead after gemm_qkv

    prep<<<5120, 256, 0, stream>>>((const float4*)x, xh, wa, waT, wp, wpT);
    gemm_qkv<<<dim3(12, 32), 512, 0, stream>>>(xh, waT, ba, qn, kP, vP);
    attn<<<dim3(32, 128), 512, 0, stream>>>(qn, kP, vP, y);
    gemm_proj<<<dim3(8, 32), 512, 0, stream>>>(y, wpT, bp, out, 1024);
}

// Round 10
// 257.894 us; speedup vs baseline: 1.0182x; 1.0182x over previous
//
#include <hip/hip_runtime.h>

// TreeAttentionV2: B=8, T=1024, C=1024 (L=4,R=256), H=16, hd=64.
// Pipeline (all fp16 MFMA, fp32 accumulate):
//   1. prep:      x fp32 -> xh fp16 AND both weight transposes (one launch)
//   2. gemm_qkv:  qn/kP/vP = xh @ waT^T + b_attn. 256x256x64 8-phase; fused-pack epilogue
//                 (16x16 fragment orders, proven); XCD swizzle.
//   3. attn v11:  WAVE-INDEPENDENT, barrier-free, ZERO LDS. Each wave owns one
//                 (bh, 32-q-row) unit and loops the FULL k=1024 twice:
//                 pass A: QK(32x32x16) + exp2 -> denominator l (register shfl only).
//                 pass B: recompute e (bitwise-identical), normalize+threshold in fp16,
//                 repack to PV A-frags via v_permlane32_swap_b32 (r9 correctness-proven),
//                 PV accumulate; y written straight from accumulators. No __syncthreads.
//   4. gemm_proj: out = y @ wpT^T + b_proj (256x128 8-phase, 1 exact round, XCD swizzle)
//
// Workspace (88 MiB):
//   [0,16M)   y ; [16M,32M) qn ; [32M,48M) kP ; [48M,64M) vP
//   [64M,70M) waT ; [70M,72M) wpT ; [72M,88M) xh (dead after gemm_qkv)

typedef _Float16 half8 __attribute__((ext_vector_type(8)));
typedef _Float16 half4_t __attribute__((ext_vector_type(4)));
typedef float floatx4 __attribute__((ext_vector_type(4)));
typedef float floatx16 __attribute__((ext_vector_type(16)));
typedef unsigned int uint4v __attribute__((ext_vector_type(4)));

__device__ __forceinline__ void gl2lds16(const void* gsrc, void* lds) {
    __builtin_amdgcn_global_load_lds(
        (const __attribute__((address_space(1))) unsigned int*)gsrc,
        (__attribute__((address_space(3))) unsigned int*)lds,
        16, 0, 0);
}

// pack two f32 -> dword of 2 fp16
__device__ __forceinline__ unsigned pkh(float a, float b) {
    _Float16 ha = (_Float16)a, hb = (_Float16)b;
    unsigned short ua = __builtin_bit_cast(unsigned short, ha);
    unsigned short ub = __builtin_bit_cast(unsigned short, hb);
    return (unsigned)ua | ((unsigned)ub << 16);
}

// ---------------- prep: conv_x (blocks 0..4095) + weight transposes (4096..5119) ----------
__global__ __launch_bounds__(256) void prep(const float4* __restrict__ x4,
                                            _Float16* __restrict__ xh,
                                            const float* __restrict__ wa,
                                            _Float16* __restrict__ waT,
                                            const float* __restrict__ wp,
                                            _Float16* __restrict__ wpT) {
    __shared__ _Float16 t[64 * 65];
    int bid = blockIdx.x;
    if (bid < 4096) {
        int idx = bid * 256 + threadIdx.x;
#pragma unroll
        for (int i = idx; i < 2097152; i += 1048576) {
            float4 v = x4[i];
            half4_t h = { (_Float16)v.x, (_Float16)v.y, (_Float16)v.z, (_Float16)v.w };
            *(half4_t*)(xh + (size_t)i * 4) = h;
        }
    } else {
        int tt = bid - 4096;
        int by = tt & 15, bx = tt >> 4;
        const float* in = wa; _Float16* out = waT; int C = 3072;
        if (bx >= 48) { bx -= 48; in = wp; out = wpT; C = 1024; }
#pragma unroll
        for (int it = 0; it < 16; ++it) {
            int idx = it * 256 + threadIdx.x;
            int r = idx >> 6, c = idx & 63;
            t[c * 65 + r] = (_Float16)in[(size_t)(by * 64 + r) * C + bx * 64 + c];
        }
        __syncthreads();
#pragma unroll
        for (int it = 0; it < 16; ++it) {
            int idx = it * 256 + threadIdx.x;
            int rn = idx >> 6, ck = idx & 63;
            out[(size_t)(bx * 64 + rn) * 1024 + by * 64 + ck] = t[rn * 65 + ck];
        }
    }
}

// common pipeline helpers
#define GBAR __builtin_amdgcn_s_barrier()
#define WLGKM do { asm volatile("s_waitcnt lgkmcnt(0)" ::: "memory"); } while (0)
#define WVM2  do { asm volatile("s_waitcnt vmcnt(2)"   ::: "memory"); } while (0)
#define WVM4  do { asm volatile("s_waitcnt vmcnt(4)"   ::: "memory"); } while (0)
#define WVM0  do { asm volatile("s_waitcnt vmcnt(0)"   ::: "memory"); } while (0)

// ================= gemm_qkv: 256x256 8-phase + fused-pack epilogue + XCD swizzle ======
// kP chunk c holds K[t=(c>>7&63)*16+(c&15)][d=(c>>6&1)*32+((c>>4)&3)*8+j]  (c per bh<<13)
// vP chunk c holds V^T[d=((c&255)>>6)*16+(c&15)][k=(c>>8&31)*32+((c>>4)&3)*8+j] (per bh<<13)

#define WLDA(buf, rg)                                                                         \
    do {                                                                                      \
        _Pragma("unroll") for (int i = 0; i < 4; ++i) {                                       \
            int r_ = wm * 128 + ((rg) * 4 + i) * 16 + l15;                                    \
            _Pragma("unroll") for (int kk = 0; kk < 2; ++kk)                                  \
                a[i][kk] = *(const half8*)(sA + (buf) * 32768 + r_ * 128 +                    \
                                           ((((kk << 2) + quad) ^ (r_ & 7)) << 4));           \
        }                                                                                     \
    } while (0)

#define WLDB(buf, cg, bb)                                                                     \
    do {                                                                                      \
        _Pragma("unroll") for (int j = 0; j < 2; ++j) {                                       \
            int r_ = wn * 64 + ((cg) * 2 + j) * 16 + l15;                                     \
            _Pragma("unroll") for (int kk = 0; kk < 2; ++kk)                                  \
                bb[j][kk] = *(const half8*)(sB + (buf) * 32768 + r_ * 128 +                   \
                                            ((((kk << 2) + quad) ^ (r_ & 7)) << 4));          \
        }                                                                                     \
    } while (0)

#define WMMA(rg, cg, bb)                                                                      \
    do {                                                                                      \
        __builtin_amdgcn_s_setprio(1);                                                        \
        _Pragma("unroll") for (int kk = 0; kk < 2; ++kk)                                      \
            _Pragma("unroll") for (int i = 0; i < 4; ++i)                                     \
                _Pragma("unroll") for (int j = 0; j < 2; ++j)                                  \
                    acc[(rg) * 4 + i][(cg) * 2 + j] = __builtin_amdgcn_mfma_f32_16x16x32_f16( \
                        a[i][kk], bb[j][kk], acc[(rg) * 4 + i][(cg) * 2 + j], 0, 0, 0);       \
        __builtin_amdgcn_s_setprio(0);                                                        \
    } while (0)

__global__ __launch_bounds__(512, 2) void gemm_qkv(const _Float16* __restrict__ A,
                                                   const _Float16* __restrict__ BT,
                                                   const float* __restrict__ bias,
                                                   _Float16* __restrict__ qno,
                                                   _Float16* __restrict__ kPo,
                                                   _Float16* __restrict__ vPo) {
    __shared__ __attribute__((aligned(16))) char lds[131072];
    char* sA = lds;           // + buf*32768 + half*16384 + rnd*8192
    char* sB = lds + 65536;
    int tid = threadIdx.x;
    int W = tid >> 6, lane = tid & 63, quad = lane >> 4, l15 = lane & 15;
    int wm = W >> 2, wn = W & 3;
    int flat = blockIdx.y * 12 + blockIdx.x;
    int swz = (flat & 7) * 48 + (flat >> 3);   // bijective, 384 % 8 == 0
    int m0 = (swz / 12) * 256, n0 = (swz % 12) * 256;

    auto stA = [&](int buf, int half, int k0) {
#pragma unroll
        for (int rnd = 0; rnd < 2; ++rnd) {
            int c = rnd * 512 + tid;
            int row = c >> 3;
            int q = (c & 7) ^ (row & 7);
            const _Float16* src = A + (size_t)(m0 + half * 128 + row) * 1024 + k0 + q * 8;
            int off = __builtin_amdgcn_readfirstlane(buf * 32768 + half * 16384 +
                                                     rnd * 8192 + (W << 10));
            gl2lds16(src, sA + off);
        }
    };
    auto stB = [&](int buf, int half, int k0) {
#pragma unroll
        for (int rnd = 0; rnd < 2; ++rnd) {
            int c = rnd * 512 + tid;
            int row = c >> 3;
            int q = (c & 7) ^ (row & 7);
            const _Float16* src = BT + (size_t)(n0 + half * 128 + row) * 1024 + k0 + q * 8;
            int off = __builtin_amdgcn_readfirstlane(buf * 32768 + half * 16384 +
                                                     rnd * 8192 + (W << 10));
            gl2lds16(src, sB + off);
        }
    };

    half8 a[4][2], b0[2][2], b1[2][2];
    floatx4 acc[8][4] = {};

    stA(0, 0, 0); stA(0, 1, 0);
    stB(0, 0, 0); stB(0, 1, 0);
    stB(1, 0, 64); stB(1, 1, 64);
    WVM4;
    GBAR;

#pragma unroll 1
    for (int t = 0; t < 16; t += 2) {
        int k1 = (t + 1) << 6;
        int k2 = ((t + 2) & 15) << 6;   // wraps last iter: garbage into dead bufs
        int k3 = ((t + 3) & 15) << 6;
        WLDA(0, 0); WLDB(0, 0, b0); stA(1, 0, k1);
        GBAR; WLGKM; WMMA(0, 0, b0); GBAR;                 // P1
        WLDB(0, 1, b1); stA(1, 1, k1);
        GBAR; WLGKM; WMMA(0, 1, b1); GBAR;                 // P2
        WLDA(0, 1); stB(0, 0, k2);
        GBAR; WLGKM; WMMA(1, 1, b1); GBAR;                 // P3
        stB(0, 1, k2); WVM4;
        GBAR; WLGKM; WMMA(1, 0, b0); GBAR;                 // P4
        WLDA(1, 0); WLDB(1, 0, b0); stA(0, 0, k2);
        GBAR; WLGKM; WMMA(0, 0, b0); GBAR;                 // P5
        WLDB(1, 1, b1); stA(0, 1, k2);
        GBAR; WLGKM; WMMA(0, 1, b1); GBAR;                 // P6
        WLDA(1, 1); stB(1, 0, k3);
        GBAR; WLGKM; WMMA(1, 1, b1); GBAR;                 // P7
        stB(1, 1, k3); WVM4;
        GBAR; WLGKM; WMMA(1, 0, b0); GBAR;                 // P8
    }

    // ---- fused-pack epilogue: two column-half passes (128 cols each) ----
    WVM0;          // trailing prefetch DMA must land before LDS reuse
    GBAR;
    int sec = n0 >> 10;          // 0=Q 1=K 2=V (256-tiles never straddle 1024)
    int b = m0 >> 10;            // batch (BM=256 stays within one b)
    int tb = m0 & 1023;          // token base
#pragma unroll 1
    for (int p = 0; p < 2; ++p) {
        if (p) __syncthreads();          // pass-0 reads done before restage
        if (sec == 2) {
            // V: stage transposed [lc=128][m=256], row stride 528B
            if ((wn >> 1) == p) {
#pragma unroll
                for (int cf = 0; cf < 4; ++cf) {
                    int lc = (wn & 1) * 64 + cf * 16 + l15;
                    float bv = bias[n0 + wn * 64 + cf * 16 + l15];
#pragma unroll
                    for (int rf = 0; rf < 8; ++rf) {
                        int m = wm * 128 + rf * 16 + quad * 4;   // m&7 in {0,4}: 8B aligned
                        half4_t h4;
#pragma unroll
                        for (int r = 0; r < 4; ++r) h4[r] = (_Float16)(acc[rf][cf][r] + bv);
                        *(half4_t*)(lds + lc * 528 + m * 2) = h4;
                    }
                }
            }
            __syncthreads();
            int l15v = tid & 15;
            int moct = W * 4 + ((tid >> 4) & 3);     // m-octet 0..31
            int t = tb + moct * 8;
            int kbv = (t >> 5) & 31, quad_v = (t >> 3) & 3;
            int nbV = (n0 & 1023) + p * 128;
#pragma unroll
            for (int i = 0; i < 8; ++i) {
                int hh = i >> 2, cf = i & 3;
                int n = hh * 64 + cf * 16 + l15v;
                half8 v = *(const half8*)(lds + n * 528 + (moct << 4));
                int gcol = nbV + n;
                int h = gcol >> 6, d = gcol & 63;
                size_t chunk = (size_t)((b * 16 + h) * 32 + kbv) * 256 +
                               (d >> 4) * 64 + quad_v * 16 + (d & 15);
                *(half8*)(vPo + chunk * 8) = v;
            }
        } else {
            // Q/K: stage [m=256][lc=128], row stride 272B
            if ((wn >> 1) == p) {
#pragma unroll
                for (int cf = 0; cf < 4; ++cf) {
                    int lc = (wn & 1) * 64 + cf * 16 + l15;
                    float bv = bias[n0 + wn * 64 + cf * 16 + l15];
#pragma unroll
                    for (int rf = 0; rf < 8; ++rf) {
                        int m = wm * 128 + rf * 16 + quad * 4;
#pragma unroll
                        for (int r = 0; r < 4; ++r)
                            *(_Float16*)(lds + (m + r) * 272 + lc * 2) =
                                (_Float16)(acc[rf][cf][r] + bv);
                    }
                }
            }
            __syncthreads();
            int nb = (n0 & 1023) + p * 128;
            if (sec == 0) {
                int noct = tid & 15;
#pragma unroll
                for (int i = 0; i < 8; ++i) {
                    int m = i * 32 + (tid >> 4);
                    half8 v = *(const half8*)(lds + m * 272 + (noct << 4));
                    *(half8*)(qno + (size_t)(b * 1024 + tb + m) * 1024 + nb + noct * 8) = v;
                }
            } else {
                int l15k = tid & 15, noct = (tid >> 4) & 15;
#pragma unroll
                for (int i = 0; i < 8; ++i) {
                    int mb = i * 2 + (tid >> 8);
                    int m = mb * 16 + l15k;
                    half8 v = *(const half8*)(lds + m * 272 + (noct << 4));
                    int gcol = nb + noct * 8;
                    int h = gcol >> 6, d0 = gcol & 63;
                    int t = tb + m;
                    size_t chunk = (size_t)((b * 16 + h) * 64 + (t >> 4)) * 128 +
                                   (d0 >> 5) * 64 + ((d0 >> 3) & 3) * 16 + l15k;
                    *(half8*)(kPo + chunk * 8) = v;
                }
            }
        }
    }
}

// ================= gemm_proj: 256x128 8-phase, f32 out, XCD swizzle =================
#define LDA(buf, rg)                                                                          \
    do {                                                                                      \
        _Pragma("unroll") for (int i = 0; i < 2; ++i) {                                       \
            int r_ = wm * 64 + ((rg) * 2 + i) * 16 + l15;                                     \
            _Pragma("unroll") for (int kk = 0; kk < 2; ++kk)                                  \
                a[i][kk] = *(const half8*)(sA + (buf) * 32768 + r_ * 128 +                    \
                                           ((((kk << 2) + quad) ^ (r_ & 7)) << 4));           \
        }                                                                                     \
    } while (0)

#define LDB(buf, cg, bb)                                                                      \
    do {                                                                                      \
        _Pragma("unroll") for (int j = 0; j < 2; ++j) {                                       \
            int r_ = wn * 64 + ((cg) * 2 + j) * 16 + l15;                                     \
            _Pragma("unroll") for (int kk = 0; kk < 2; ++kk)                                  \
                bb[j][kk] = *(const half8*)(sB + (buf) * 16384 + r_ * 128 +                   \
                                            ((((kk << 2) + quad) ^ (r_ & 7)) << 4));          \
        }                                                                                     \
    } while (0)

#define MMA(rg, cg, bb)                                                                       \
    do {                                                                                      \
        __builtin_amdgcn_s_setprio(1);                                                        \
        _Pragma("unroll") for (int kk = 0; kk < 2; ++kk)                                      \
            _Pragma("unroll") for (int i = 0; i < 2; ++i)                                     \
                _Pragma("unroll") for (int j = 0; j < 2; ++j)                                  \
                    acc[(rg) * 2 + i][(cg) * 2 + j] = __builtin_amdgcn_mfma_f32_16x16x32_f16( \
                        a[i][kk], bb[j][kk], acc[(rg) * 2 + i][(cg) * 2 + j], 0, 0, 0);       \
        __builtin_amdgcn_s_setprio(0);                                                        \
    } while (0)

__global__ __launch_bounds__(512, 2) void gemm_proj(const _Float16* __restrict__ A,
                                                    const _Float16* __restrict__ BT,
                                                    const float* __restrict__ bias,
                                                    float* __restrict__ o0, int N) {
    __shared__ __attribute__((aligned(16))) char lds[98304];
    char* sA = lds;
    char* sB = lds + 65536;
    int tid = threadIdx.x;
    int W = tid >> 6, lane = tid & 63, quad = lane >> 4, l15 = lane & 15;
    int wm = W >> 1, wn = W & 1;
    int flat = blockIdx.y * 8 + blockIdx.x;
    int swz = (flat & 7) * 32 + (flat >> 3);
    int m0 = (swz >> 3) * 256, n0 = (swz & 7) * 128;

    auto stA = [&](int buf, int half, int k0) {
#pragma unroll
        for (int rnd = 0; rnd < 2; ++rnd) {
            int c = rnd * 512 + tid;
            int row = c >> 3;
            int q = (c & 7) ^ (row & 7);
            const _Float16* src = A + (size_t)(m0 + half * 128 + row) * 1024 + k0 + q * 8;
            int off = __builtin_amdgcn_readfirstlane(buf * 32768 + half * 16384 +
                                                     rnd * 8192 + (W << 10));
            gl2lds16(src, sA + off);
        }
    };
    auto stB = [&](int buf, int half, int k0) {
        int row = tid >> 3;
        int q = (tid & 7) ^ (row & 7);
        const _Float16* src = BT + (size_t)(n0 + half * 64 + row) * 1024 + k0 + q * 8;
        int off = __builtin_amdgcn_readfirstlane(buf * 16384 + half * 8192 + (W << 10));
        gl2lds16(src, sB + off);
    };

    half8 a[2][2], b0[2][2], b1[2][2];
    floatx4 acc[4][4] = {};

    stA(0, 0, 0); stA(0, 1, 0);
    stB(0, 0, 0); stB(0, 1, 0);
    stB(1, 0, 64); stB(1, 1, 64);
    WVM2;
    GBAR;

#pragma unroll 1
    for (int t = 0; t < 16; t += 2) {
        int k1 = (t + 1) << 6;
        int k2 = ((t + 2) & 15) << 6;
        int k3 = ((t + 3) & 15) << 6;
        LDA(0, 0); LDB(0, 0, b0); stA(1, 0, k1);
        GBAR; WLGKM; MMA(0, 0, b0); GBAR;
        LDB(0, 1, b1); stA(1, 1, k1);
        GBAR; WLGKM; MMA(0, 1, b1); GBAR;
        LDA(0, 1); stB(0, 0, k2);
        GBAR; WLGKM; MMA(1, 1, b1); GBAR;
        stB(0, 1, k2); WVM2;
        GBAR; WLGKM; MMA(1, 0, b0); GBAR;
        LDA(1, 0); LDB(1, 0, b0); stA(0, 0, k2);
        GBAR; WLGKM; MMA(0, 0, b0); GBAR;
        LDB(1, 1, b1); stA(0, 1, k2);
        GBAR; WLGKM; MMA(0, 1, b1); GBAR;
        LDA(1, 1); stB(1, 0, k3);
        GBAR; WLGKM; MMA(1, 1, b1); GBAR;
        stB(1, 1, k3); WVM2;
        GBAR; WLGKM; MMA(1, 0, b0); GBAR;
    }

#pragma unroll
    for (int cf = 0; cf < 4; ++cf) {
        int gn = n0 + wn * 64 + cf * 16 + l15;
        float bv = bias[gn];
#pragma unroll
        for (int rf = 0; rf < 4; ++rf) {
            int gmBase = m0 + wm * 64 + rf * 16 + quad * 4;
#pragma unroll
            for (int r = 0; r < 4; ++r)
                o0[(size_t)(gmBase + r) * N + gn] = acc[rf][cf][r] + bv;
        }
    }
}

// ------------------------------- attention v11 -------------------------------
// Wave-independent, barrier-free, zero-LDS. grid 512 blocks x 512 thr (8 waves);
// unit = (bh, qt): block swz (XCD-chunked, 512%8==0) -> bh = swz>>2 (4 blocks/bh,
// adjacent on one XCD -> K/V L2 locality), wave W -> qt = (swz&3)*8 + W.
// Each wave: 32 q-rows x full k=1024.
//   Pass A: for kb=0..31: K-frags (proven gather), 4x mfma_32x32x16 -> s; e=exp2(s*c);
//           sum -> l (shfl_xor(32) only). No storage of e.
//   Pass B: recompute s,e (bitwise-identical); pkh+v_permlane32_swap_b32 repack to
//           PV A-frags (r9 correctness-proven); normalize+threshold fp16; PV MFMA.
//   Write y straight from acc (per r: 32 lanes x 2B contiguous rows).
__global__ __launch_bounds__(512, 4) void attn(const _Float16* __restrict__ qn,
                                               const _Float16* __restrict__ kP,
                                               const _Float16* __restrict__ vP,
                                               _Float16* __restrict__ y) {
    int tid = threadIdx.x;
    int W = tid >> 6, lane = tid & 63;
    int l31 = lane & 31, hi = lane >> 5;
    int flat = blockIdx.x;
    int swz = (flat & 7) * 64 + (flat >> 3);      // bijective, 512 % 8 == 0
    int bh = swz >> 2;
    int qt = (swz & 3) * 8 + W;
    int b = bh >> 4, h = bh & 15;
    int q0 = qt * 32;

    const _Float16* kPb = kP + (size_t)bh * 8192 * 8;   // this head's 8192 chunks
    const _Float16* vPb = vP + (size_t)bh * 8192 * 8;

    // --- Q as 32x32x16 B-frags: lane holds Q[q=l31][d=ks*16+hi*8+j] ---
    half8 bq[4];
#pragma unroll
    for (int ks = 0; ks < 4; ++ks)
        bq[ks] = *(const half8*)(qn + (size_t)(b * 1024 + q0 + l31) * 1024 +
                                 h * 64 + ks * 16 + hi * 8);

    // --- Pass A: denominator l over full k (no e storage) ---
    float lpA = 0.f, lpB = 0.f;
#pragma unroll 2
    for (int kb = 0; kb < 32; ++kb) {
        // t = kb*32 + l31 -> chunk base (t>>4)*128 + (t&15)
        int cbase = (kb * 2 + (l31 >> 4)) * 128 + (l31 & 15);
        half8 ak0 = *(const half8*)(kPb + (size_t)(cbase + hi * 16) * 8);
        half8 ak1 = *(const half8*)(kPb + (size_t)(cbase + (2 + hi) * 16) * 8);
        half8 ak2 = *(const half8*)(kPb + (size_t)(cbase + 64 + hi * 16) * 8);
        half8 ak3 = *(const half8*)(kPb + (size_t)(cbase + 64 + (2 + hi) * 16) * 8);
        floatx16 s = {};
        __builtin_amdgcn_s_setprio(1);
        s = __builtin_amdgcn_mfma_f32_32x32x16_f16(ak0, bq[0], s, 0, 0, 0);
        s = __builtin_amdgcn_mfma_f32_32x32x16_f16(ak1, bq[1], s, 0, 0, 0);
        s = __builtin_amdgcn_mfma_f32_32x32x16_f16(ak2, bq[2], s, 0, 0, 0);
        s = __builtin_amdgcn_mfma_f32_32x32x16_f16(ak3, bq[3], s, 0, 0, 0);
        __builtin_amdgcn_s_setprio(0);
        float e[16];
#pragma unroll
        for (int r = 0; r < 16; ++r)
            e[r] = __builtin_amdgcn_exp2f(s[r] * 0.18033688f);   // exp(s/8); clamp dead
        lpA += ((e[0] + e[1]) + (e[2] + e[3])) + ((e[4] + e[5]) + (e[6] + e[7]));
        lpB += ((e[8] + e[9]) + (e[10] + e[11])) + ((e[12] + e[13]) + (e[14] + e[15]));
    }
    half8 inv8, t8, z8;
#pragma unroll
    for (int j = 0; j < 8; ++j) { t8[j] = (_Float16)(-0.001f); z8[j] = (_Float16)0.f; }
    {
        float lp = lpA + lpB;
        lp += __shfl_xor(lp, 32);      // lanes l and l+32 share q = l31
        _Float16 invh = (_Float16)(1.0f / lp);
#pragma unroll
        for (int j = 0; j < 8; ++j) inv8[j] = invh;
    }

    // --- Pass B: recompute e (bitwise-identical), repack, normalize, PV ---
    floatx16 acc0 = {}, acc1 = {};
#pragma unroll 2
    for (int kb = 0; kb < 32; ++kb) {
        int cbase = (kb * 2 + (l31 >> 4)) * 128 + (l31 & 15);
        half8 ak0 = *(const half8*)(kPb + (size_t)(cbase + hi * 16) * 8);
        half8 ak1 = *(const half8*)(kPb + (size_t)(cbase + (2 + hi) * 16) * 8);
        half8 ak2 = *(const half8*)(kPb + (size_t)(cbase + 64 + hi * 16) * 8);
        half8 ak3 = *(const half8*)(kPb + (size_t)(cbase + 64 + (2 + hi) * 16) * 8);
        floatx16 s = {};
        __builtin_amdgcn_s_setprio(1);
        s = __builtin_amdgcn_mfma_f32_32x32x16_f16(ak0, bq[0], s, 0, 0, 0);
        s = __builtin_amdgcn_mfma_f32_32x32x16_f16(ak1, bq[1], s, 0, 0, 0);
        s = __builtin_amdgcn_mfma_f32_32x32x16_f16(ak2, bq[2], s, 0, 0, 0);
        s = __builtin_amdgcn_mfma_f32_32x32x16_f16(ak3, bq[3], s, 0, 0, 0);
        __builtin_amdgcn_s_setprio(0);
        float e[16];
#pragma unroll
        for (int r = 0; r < 16; ++r)
            e[r] = __builtin_amdgcn_exp2f(s[r] * 0.18033688f);
        // repack rows k'=(r&3)+8(r>>2)+4hi -> A-frag k'=8hi+j (r9-proven mapping)
        half8 pd[2];
#pragma unroll
        for (int c2 = 0; c2 < 2; ++c2) {
            int o = c2 * 8;
            unsigned P01 = pkh(e[o + 0], e[o + 1]);
            unsigned P23 = pkh(e[o + 2], e[o + 3]);
            unsigned P45 = pkh(e[o + 4], e[o + 5]);
            unsigned P67 = pkh(e[o + 6], e[o + 7]);
            asm("v_permlane32_swap_b32 %0, %1" : "+v"(P01), "+v"(P45));
            asm("v_permlane32_swap_b32 %0, %1" : "+v"(P23), "+v"(P67));
            uint4v F = { P01, P23, P45, P67 };
            pd[c2] = __builtin_bit_cast(half8, F);
            pd[c2] = pd[c2] * inv8 + t8;                       // v_pk_fma_f16
            pd[c2] = __builtin_elementwise_max(pd[c2], z8);    // v_pk_max_f16
        }
        // PV: k-16-chunk kc = kb*2 + c2; V chunk = kb*256 + (l31>>4)*64 +
        //     (c2*2+hi)*16 + (l31&15); d-half at +128 chunks.
#pragma unroll
        for (int c2 = 0; c2 < 2; ++c2) {
            int vbase = kb * 256 + (l31 >> 4) * 64 + (c2 * 2 + hi) * 16 + (l31 & 15);
            half8 bv0 = *(const half8*)(vPb + (size_t)vbase * 8);
            half8 bv1 = *(const half8*)(vPb + (size_t)(vbase + 128) * 8);
            __builtin_amdgcn_s_setprio(1);
            acc0 = __builtin_amdgcn_mfma_f32_32x32x16_f16(pd[c2], bv0, acc0, 0, 0, 0);
            acc1 = __builtin_amdgcn_mfma_f32_32x32x16_f16(pd[c2], bv1, acc1, 0, 0, 0);
            __builtin_amdgcn_s_setprio(0);
        }
    }

    // --- write y straight from acc: D col d = dh*32+l31, row q = (r&3)+8(r>>2)+4hi ---
    _Float16* yb = y + (size_t)(b * 1024 + q0) * 1024 + h * 64;
#pragma unroll
    for (int r = 0; r < 16; ++r) {
        int q = (r & 3) + 8 * (r >> 2) + 4 * hi;
        yb[(size_t)q * 1024 + l31] = (_Float16)acc0[r];
        yb[(size_t)q * 1024 + 32 + l31] = (_Float16)acc1[r];
    }
}

// ------------------------------- launcher -------------------------------
extern "C" void kernel_launch(void* const* d_in, const int* in_sizes, int n_in,
                              void* d_out, int out_size, void* d_ws, size_t ws_size,
                              hipStream_t stream) {
    const float* x  = (const float*)d_in[0];
    const float* wa = (const float*)d_in[1];
    const float* ba = (const float*)d_in[2];
    const float* wp = (const float*)d_in[3];
    const float* bp = (const float*)d_in[4];
    float* out = (float*)d_out;

    char* ws = (char*)d_ws;
    _Float16* y   = (_Float16*)(ws);                    // [0,16M)   attn out
    _Float16* qn  = (_Float16*)(ws + 16777216);         // [16M,32M)
    _Float16* kP  = (_Float16*)(ws + 33554432);         // [32M,48M)
    _Float16* vP  = (_Float16*)(ws + 50331648);         // [48M,64M)
    _Float16* waT = (_Float16*)(ws + 67108864);         // [64M,70M)
    _Float16* wpT = (_Float16*)(ws + 73400320);         // [70M,72M)
    _Float16* xh  = (_Float16*)(ws + 75497472);         // [72M,88M) dead after gemm_qkv

    prep<<<5120, 256, 0, stream>>>((const float4*)x, xh, wa, waT, wp, wpT);
    gemm_qkv<<<dim3(12, 32), 512, 0, stream>>>(xh, waT, ba, qn, kP, vP);
    attn<<<512, 512, 0, stream>>>(qn, kP, vP, y);
    gemm_proj<<<dim3(8, 32), 512, 0, stream>>>(y, wpT, bp, out, 1024);
}